// Round 2
// baseline (74.908 us; speedup 1.0000x reference)
//
#include <hip/hip_runtime.h>

#define NF 64
#define LEN 299592
#define V0 37448            // voxel region start in octree
#define MEAN3_OFF 7607      // 4096 + 3511
#define N_MEAN3 585         // 4096 - 3511
#define MASK_SCRATCH 8192   // float index (per feature) where m4 bitmask lives temporarily
#define NZEROS 32183        // 7607 + 24576
#define PT 1024             // k_prune threads
#define PW (PT / 64)        // k_prune waves

// K1: per-feature prune-mask cascade. One block per feature.
// lt[] holds "value < EPS" bits for positions [0,65536) (post-zeroing state).
// Level masks m[j] = lt_enter[dl+j] || m[parent], parent=(j-st)>>3 (if parent<j).
// Final product: level-4 mask (32768 bits) -> stored in out scratch region.
__global__ __launch_bounds__(PT) void k_prune_masks(const float* __restrict__ in,
                                                    float* __restrict__ out) {
    __shared__ unsigned long long lt[1024];   // 65536 bits
    __shared__ unsigned long long mk[512];    // up to 32768 mask bits
    const int f = blockIdx.x;
    const float* src = in + (size_t)f * LEN;
    const int tid = threadIdx.x;
    const int lane = tid & 63, wv = tid >> 6;

    for (int g = wv; g < 1024; g += PW) {
        int p = (g << 6) + lane;
        unsigned long long bal = __ballot(src[p] < 1e-5f);
        if (lane == 0) lt[g] = bal;
    }
    __syncthreads();

    const int DLs[5] = {8, 64, 512, 4096, 32768};
    const int STs[5] = {0, 8, 72, 584, 4680};
    for (int lev = 0; lev < 5; ++lev) {
        const int dl = DLs[lev], st = STs[lev], en = st + dl;
        const int ng = (dl + 63) >> 6;
        // mask compute (reads lt, writes mk)
        for (int g = wv; g < ng; g += PW) {
            int j = (g << 6) + lane;
            bool m = false;
            if (j < dl) {
                int a = j;
                for (;;) {
                    int p = dl + a;
                    m = m || ((lt[p >> 6] >> (p & 63)) & 1ULL);
                    if (a >= st) {
                        int pa = (a - st) >> 3;
                        if (pa < a) { a = pa; continue; }
                    }
                    break;
                }
            }
            unsigned long long bal = __ballot(m);
            if (lane == 0) mk[g] = bal;
        }
        __syncthreads();
        if (lev == 4) {
            unsigned long long* mptr =
                (unsigned long long*)(out + (size_t)f * LEN + MASK_SCRATCH);
            if (tid < 512) mptr[tid] = mk[tid];
            return;
        }
        // apply zeroing to lt over [dl, en+8*dl) (reads mk, writes lt)
        const int hi = ((en + 8 * dl) + 63) >> 6;   // <= 586 for lev 3
        for (int g = (dl >> 6) + wv; g < hi; g += PW) {
            int p = (g << 6) + lane;
            bool b = (lt[g] >> lane) & 1ULL;
            if (p >= dl && p < 2 * dl) {
                int q = p - dl;
                b = b || ((mk[q >> 6] >> (q & 63)) & 1ULL);
            }
            if (p >= en && p < en + 8 * dl) {
                int q = (p - en) >> 3;
                b = b || ((mk[q >> 6] >> (q & 63)) & 1ULL);
            }
            unsigned long long bal = __ballot(b);
            if (lane == 0) lt[g] = bal;
        }
        __syncthreads();
    }
}

// K2: bulk. One thread per (f, j) level-4 node: read its 8 voxel children.
// j >= 3511: shared mask m4[j]; write mean4 and the pruned children (p>=65536).
// j <  3511: per-child masks m4[4680+8j+c] (byte 585+j of the bitset); write mean4 only.
__global__ __launch_bounds__(256) void k_bulk(const float* __restrict__ in,
                                              float* __restrict__ out) {
    int t = blockIdx.x * 256 + threadIdx.x;      // 64*32768 total
    int f = t >> 15, j = t & 32767;
    size_t base = (size_t)f * LEN;
    const unsigned char* mb =
        (const unsigned char*)(out + base + MASK_SCRATCH);
    const float4* s = (const float4*)(in + base + V0 + 8 * (size_t)j);
    float4 a = s[0], b = s[1];
    if (j >= 3511) {
        bool m = (mb[j >> 3] >> (j & 7)) & 1;
        float mean;
        if (m) {
            a = make_float4(0.f, 0.f, 0.f, 0.f);
            b = a;
            mean = 0.f;
        } else {
            mean = (a.x + a.y + a.z + a.w + b.x + b.y + b.z + b.w) * 0.125f;
        }
        out[base + 32768 + j] = mean;
        float4* d = (float4*)(out + base + V0 + 8 * (size_t)j);
        d[0] = a;
        d[1] = b;
    } else {
        unsigned cmask = mb[585 + j];            // bits 4680+8j .. +8, byte-aligned
        if (cmask & 1)   a.x = 0.f;
        if (cmask & 2)   a.y = 0.f;
        if (cmask & 4)   a.z = 0.f;
        if (cmask & 8)   a.w = 0.f;
        if (cmask & 16)  b.x = 0.f;
        if (cmask & 32)  b.y = 0.f;
        if (cmask & 64)  b.z = 0.f;
        if (cmask & 128) b.w = 0.f;
        out[base + 32768 + j] =
            (a.x + a.y + a.z + a.w + b.x + b.y + b.z + b.w) * 0.125f;
    }
}

// K3: mean3 tail: out[7607+t] = mean of mean4[8t..8t+8), t in [0,585).
__global__ __launch_bounds__(256) void k_mean3(float* __restrict__ out) {
    int t = blockIdx.x * 256 + threadIdx.x;
    if (t >= N_MEAN3) return;
    size_t base = (size_t)blockIdx.y * LEN;
    const float4* s = (const float4*)(out + base + 32768 + 8 * (size_t)t);
    float4 a = s[0], b = s[1];
    out[base + MEAN3_OFF + t] =
        (a.x + a.y + a.z + a.w + b.x + b.y + b.z + b.w) * 0.125f;
}

// K4: zeros for [0,7607) and [8192,32768) (also clears the mask scratch).
__global__ __launch_bounds__(256) void k_zeros(float* __restrict__ out) {
    int p = blockIdx.x * 256 + threadIdx.x;
    if (p >= NZEROS) return;
    int pos = (p < MEAN3_OFF) ? p : (8192 + (p - MEAN3_OFF));
    out[(size_t)blockIdx.y * LEN + pos] = 0.f;
}

extern "C" void kernel_launch(void* const* d_in, const int* in_sizes, int n_in,
                              void* d_out, int out_size, void* d_ws, size_t ws_size,
                              hipStream_t stream) {
    const float* in = (const float*)d_in[0];
    float* out = (float*)d_out;

    k_prune_masks<<<NF, PT, 0, stream>>>(in, out);
    k_bulk<<<(NF * 32768) / 256, 256, 0, stream>>>(in, out);
    k_mean3<<<dim3(3, NF), 256, 0, stream>>>(out);
    k_zeros<<<dim3(126, NF), 256, 0, stream>>>(out);
}

// Round 3
// 61.477 us; speedup vs baseline: 1.2185x; 1.2185x over previous
//
#include <hip/hip_runtime.h>

#define NF 64
#define LEN 299592
#define V0 37448            // voxel region start in octree
#define MEAN3_OFF 7607      // 4096 + 3511
#define N_MEAN3 585         // 4096 - 3511
#define LT_SCRATCH 0        // float idx (per feature): 65536-bit lt bitset (8 KB)
#define MASK_SCRATCH 8192   // float idx (per feature): m4 bitmask (4 KB)
#define NZEROS 32183        // 7607 + 24576
#define PT 1024             // k_cascade threads
#define PW (PT / 64)        // k_cascade waves

// K1a: raw "< EPS" ballot over positions [0,65536) of every feature.
// One thread per position; lane0 of each wave stores one 64-bit word into the
// out-buffer scratch region (later cleared by k_zeros).
__global__ __launch_bounds__(256) void k_lt(const float* __restrict__ in,
                                            float* __restrict__ out) {
    int t = blockIdx.x * 256 + threadIdx.x;      // 64 * 65536 total
    int f = t >> 16, p = t & 65535;
    bool b = in[(size_t)f * LEN + p] < 1e-5f;
    unsigned long long bal = __ballot(b);
    if ((t & 63) == 0) {
        unsigned long long* dst =
            (unsigned long long*)(out + (size_t)f * LEN + LT_SCRATCH);
        dst[p >> 6] = bal;
    }
}

// K1b: per-feature prune-mask cascade. One block per feature.
// lt[] holds "value < EPS" bits for positions [0,65536) (post-zeroing state).
// Level masks m[j] = lt_enter[dl+j] || m[parent], parent=(j-st)>>3 (if parent<j).
// Final product: level-4 mask (32768 bits) -> stored in out scratch region.
__global__ __launch_bounds__(PT) void k_cascade(float* __restrict__ out) {
    __shared__ unsigned long long lt[1024];   // 65536 bits
    __shared__ unsigned long long mk[512];    // up to 32768 mask bits
    const int f = blockIdx.x;
    const size_t base = (size_t)f * LEN;
    const int tid = threadIdx.x;
    const int lane = tid & 63, wv = tid >> 6;

    {
        const unsigned long long* src =
            (const unsigned long long*)(out + base + LT_SCRATCH);
        lt[tid] = src[tid];
    }
    __syncthreads();

    const int DLs[5] = {8, 64, 512, 4096, 32768};
    const int STs[5] = {0, 8, 72, 584, 4680};
    for (int lev = 0; lev < 5; ++lev) {
        const int dl = DLs[lev], st = STs[lev], en = st + dl;
        const int ng = (dl + 63) >> 6;
        // mask compute (reads lt, writes mk)
        for (int g = wv; g < ng; g += PW) {
            int j = (g << 6) + lane;
            bool m = false;
            if (j < dl) {
                int a = j;
                for (;;) {
                    int p = dl + a;
                    m = m || ((lt[p >> 6] >> (p & 63)) & 1ULL);
                    if (a >= st) {
                        int pa = (a - st) >> 3;
                        if (pa < a) { a = pa; continue; }
                    }
                    break;
                }
            }
            unsigned long long bal = __ballot(m);
            if (lane == 0) mk[g] = bal;
        }
        __syncthreads();
        if (lev == 4) {
            unsigned long long* mptr =
                (unsigned long long*)(out + base + MASK_SCRATCH);
            if (tid < 512) mptr[tid] = mk[tid];
            return;
        }
        // apply zeroing to lt over [dl, en+8*dl) (reads mk, writes lt)
        const int hi = ((en + 8 * dl) + 63) >> 6;   // <= 586 for lev 3
        for (int g = (dl >> 6) + wv; g < hi; g += PW) {
            int p = (g << 6) + lane;
            bool b = (lt[g] >> lane) & 1ULL;
            if (p >= dl && p < 2 * dl) {
                int q = p - dl;
                b = b || ((mk[q >> 6] >> (q & 63)) & 1ULL);
            }
            if (p >= en && p < en + 8 * dl) {
                int q = (p - en) >> 3;
                b = b || ((mk[q >> 6] >> (q & 63)) & 1ULL);
            }
            unsigned long long bal = __ballot(b);
            if (lane == 0) lt[g] = bal;
        }
        __syncthreads();
    }
}

// K2: bulk. One thread per (f, j) level-4 node: read its 8 voxel children.
// j >= 3511: shared mask m4[j]; write mean4 and the pruned children (p>=65536).
// j <  3511: per-child masks m4[4680+8j+c] (byte 585+j of the bitset); write mean4 only.
__global__ __launch_bounds__(256) void k_bulk(const float* __restrict__ in,
                                              float* __restrict__ out) {
    int t = blockIdx.x * 256 + threadIdx.x;      // 64*32768 total
    int f = t >> 15, j = t & 32767;
    size_t base = (size_t)f * LEN;
    const unsigned char* mb =
        (const unsigned char*)(out + base + MASK_SCRATCH);
    const float4* s = (const float4*)(in + base + V0 + 8 * (size_t)j);
    float4 a = s[0], b = s[1];
    if (j >= 3511) {
        bool m = (mb[j >> 3] >> (j & 7)) & 1;
        float mean;
        if (m) {
            a = make_float4(0.f, 0.f, 0.f, 0.f);
            b = a;
            mean = 0.f;
        } else {
            mean = (a.x + a.y + a.z + a.w + b.x + b.y + b.z + b.w) * 0.125f;
        }
        out[base + 32768 + j] = mean;
        float4* d = (float4*)(out + base + V0 + 8 * (size_t)j);
        d[0] = a;
        d[1] = b;
    } else {
        unsigned cmask = mb[585 + j];            // bits 4680+8j .. +8, byte-aligned
        if (cmask & 1)   a.x = 0.f;
        if (cmask & 2)   a.y = 0.f;
        if (cmask & 4)   a.z = 0.f;
        if (cmask & 8)   a.w = 0.f;
        if (cmask & 16)  b.x = 0.f;
        if (cmask & 32)  b.y = 0.f;
        if (cmask & 64)  b.z = 0.f;
        if (cmask & 128) b.w = 0.f;
        out[base + 32768 + j] =
            (a.x + a.y + a.z + a.w + b.x + b.y + b.z + b.w) * 0.125f;
    }
}

// K3: mean3 tail: out[7607+t] = mean of mean4[8t..8t+8), t in [0,585).
__global__ __launch_bounds__(256) void k_mean3(float* __restrict__ out) {
    int t = blockIdx.x * 256 + threadIdx.x;
    if (t >= N_MEAN3) return;
    size_t base = (size_t)blockIdx.y * LEN;
    const float4* s = (const float4*)(out + base + 32768 + 8 * (size_t)t);
    float4 a = s[0], b = s[1];
    out[base + MEAN3_OFF + t] =
        (a.x + a.y + a.z + a.w + b.x + b.y + b.z + b.w) * 0.125f;
}

// K4: zeros for [0,7607) and [8192,32768) (clears both scratch regions).
__global__ __launch_bounds__(256) void k_zeros(float* __restrict__ out) {
    int p = blockIdx.x * 256 + threadIdx.x;
    if (p >= NZEROS) return;
    int pos = (p < MEAN3_OFF) ? p : (8192 + (p - MEAN3_OFF));
    out[(size_t)blockIdx.y * LEN + pos] = 0.f;
}

extern "C" void kernel_launch(void* const* d_in, const int* in_sizes, int n_in,
                              void* d_out, int out_size, void* d_ws, size_t ws_size,
                              hipStream_t stream) {
    const float* in = (const float*)d_in[0];
    float* out = (float*)d_out;

    k_lt<<<(NF * 65536) / 256, 256, 0, stream>>>(in, out);
    k_cascade<<<NF, PT, 0, stream>>>(out);
    k_bulk<<<(NF * 32768) / 256, 256, 0, stream>>>(in, out);
    k_mean3<<<dim3(3, NF), 256, 0, stream>>>(out);
    k_zeros<<<dim3(126, NF), 256, 0, stream>>>(out);
}

// Round 4
// 38.580 us; speedup vs baseline: 1.9416x; 1.5935x over previous
//
#include <hip/hip_runtime.h>

#define NF 64
#define LEN 299592
#define V0 37448            // voxel region start in octree
#define MEAN3_OFF 7607      // 4096 + 3511
#define EPSF 1e-5f
#define M3_SCRATCH 8192     // float idx (per feature): m3 bitset (64 u64 = 512 B)
#define NZEROS 32183        // 7607 + 24576

// K1: levels 0-3 prune cascade per feature (positions [0,8192) only).
// Produces the level-3 mask bitset m3[0..4096) -> out scratch (cleared later).
__global__ __launch_bounds__(1024) void k_m3(const float* __restrict__ in,
                                             float* __restrict__ out) {
    __shared__ unsigned long long lt[128];   // "<EPS" bits for positions [0,8192)
    __shared__ unsigned long long mk[64];
    const int f = blockIdx.x;
    const size_t base = (size_t)f * LEN;
    const int tid = threadIdx.x, lane = tid & 63, wv = tid >> 6;

    for (int r = 0; r < 8; ++r) {
        int p = (r << 10) + tid;
        unsigned long long bal = __ballot(in[base + p] < EPSF);
        if (lane == 0) lt[p >> 6] = bal;
    }
    __syncthreads();

    const int DLs[4] = {8, 64, 512, 4096};
    const int STs[4] = {0, 8, 72, 584};
    for (int lev = 0; lev < 4; ++lev) {
        const int dl = DLs[lev], st = STs[lev], en = st + dl;
        const int ng = (dl + 63) >> 6;
        for (int g = wv; g < ng; g += 16) {        // mask compute
            int j = (g << 6) + lane;
            bool m = false;
            if (j < dl) {
                int a = j;
                for (;;) {
                    int p = dl + a;
                    m = m || ((lt[p >> 6] >> (p & 63)) & 1ULL);
                    if (a >= st) {
                        int pa = (a - st) >> 3;
                        if (pa < a) { a = pa; continue; }
                    }
                    break;
                }
            }
            unsigned long long bal = __ballot(m);
            if (lane == 0) mk[g] = bal;
        }
        __syncthreads();
        if (lev == 3) {
            unsigned long long* mp = (unsigned long long*)(out + base + M3_SCRATCH);
            if (tid < 64) mp[tid] = mk[tid];
            return;
        }
        const int hi = ((en + 8 * dl) + 63) >> 6;  // apply zeroing to lt
        for (int g = (dl >> 6) + wv; g < hi; g += 16) {
            int p = (g << 6) + lane;
            bool b = (lt[g] >> lane) & 1ULL;
            if (p >= dl && p < 2 * dl) {
                int q = p - dl;
                b = b || ((mk[q >> 6] >> (q & 63)) & 1ULL);
            }
            if (p >= en && p < en + 8 * dl) {
                int q = (p - en) >> 3;
                b = b || ((mk[q >> 6] >> (q & 63)) & 1ULL);
            }
            unsigned long long bal = __ballot(b);
            if (lane == 0) lt[g] = bal;
        }
        __syncthreads();
    }
}

// K2: one thread per (f, j) level-4 node. Masks computed inline:
//   m4[j] = lt(in[32768+j]) || [j>=4680: lt(in[32768+q]), q=(j-4680)>>3] || m3-bit.
// j <  3511: per-child masks = lt(childval) || m4[j]; write mean only.
// j >= 3511: shared m4[j]; write mean and pruned children (positions >= 65536).
// mean3 tail fused: 8-lane shuffle reduce over mean4[0..4680) -> out[7607+t].
__global__ __launch_bounds__(256) void k_bulk(const float* __restrict__ in,
                                              float* __restrict__ out) {
    int t = blockIdx.x * 256 + threadIdx.x;      // 64*32768 total
    int f = t >> 15, j = t & 32767;
    size_t base = (size_t)f * LEN;
    const unsigned char* m3 = (const unsigned char*)(out + base + M3_SCRATCH);
    const float4* s = (const float4*)(in + base + V0 + 8 * (size_t)j);
    float4 a = s[0], b = s[1];
    float own = in[base + 32768 + j];
    float mean;
    if (j < 3511) {
        int i3 = (28088 + j) >> 3;
        bool mj = (own < EPSF) || ((m3[i3 >> 3] >> (i3 & 7)) & 1);
        if (mj) {
            mean = 0.f;
        } else {
            mean = ((a.x < EPSF ? 0.f : a.x) + (a.y < EPSF ? 0.f : a.y) +
                    (a.z < EPSF ? 0.f : a.z) + (a.w < EPSF ? 0.f : a.w) +
                    (b.x < EPSF ? 0.f : b.x) + (b.y < EPSF ? 0.f : b.y) +
                    (b.z < EPSF ? 0.f : b.z) + (b.w < EPSF ? 0.f : b.w)) * 0.125f;
        }
        out[base + 32768 + j] = mean;
    } else {
        bool m;
        if (j < 4680) {
            int i3 = (28088 + j) >> 3;
            m = (own < EPSF) || ((m3[i3 >> 3] >> (i3 & 7)) & 1);
        } else {
            int q = (j - 4680) >> 3;
            int i3 = (28088 + q) >> 3;
            m = (own < EPSF) || (in[base + 32768 + q] < EPSF) ||
                ((m3[i3 >> 3] >> (i3 & 7)) & 1);
        }
        if (m) {
            a = make_float4(0.f, 0.f, 0.f, 0.f);
            b = a;
            mean = 0.f;
        } else {
            mean = (a.x + a.y + a.z + a.w + b.x + b.y + b.z + b.w) * 0.125f;
        }
        out[base + 32768 + j] = mean;
        float4* d = (float4*)(out + base + V0 + 8 * (size_t)j);
        d[0] = a;
        d[1] = b;
    }
    // fused mean3 tail (j in [0,4680), groups of 8 within one wave)
    float v = mean;
    v += __shfl_xor(v, 1);
    v += __shfl_xor(v, 2);
    v += __shfl_xor(v, 4);
    if (j < 4680 && (j & 7) == 0)
        out[base + MEAN3_OFF + (j >> 3)] = v * 0.125f;
}

// K3: zeros for [0,7607) and [8192,32768) (also clears the m3 scratch).
__global__ __launch_bounds__(256) void k_zeros(float* __restrict__ out) {
    int p = blockIdx.x * 256 + threadIdx.x;
    if (p >= NZEROS) return;
    int pos = (p < MEAN3_OFF) ? p : (8192 + (p - MEAN3_OFF));
    out[(size_t)blockIdx.y * LEN + pos] = 0.f;
}

extern "C" void kernel_launch(void* const* d_in, const int* in_sizes, int n_in,
                              void* d_out, int out_size, void* d_ws, size_t ws_size,
                              hipStream_t stream) {
    const float* in = (const float*)d_in[0];
    float* out = (float*)d_out;

    k_m3<<<NF, 1024, 0, stream>>>(in, out);
    k_bulk<<<(NF * 32768) / 256, 256, 0, stream>>>(in, out);
    k_zeros<<<dim3(126, NF), 256, 0, stream>>>(out);
}

// Round 5
// 35.774 us; speedup vs baseline: 2.0939x; 1.0784x over previous
//
#include <hip/hip_runtime.h>

#define NF 64
#define LEN 299592
#define V0 37448            // voxel region start in octree
#define MEAN3_OFF 7607      // 4096 + 3511
#define EPSF 1e-5f

// K1: levels 0-3 prune cascade per feature (positions [0,8192) only).
// Produces the level-3 mask bitset m3[0..4096) -> d_ws (64 u64 per feature).
__global__ __launch_bounds__(1024) void k_m3(const float* __restrict__ in,
                                             unsigned long long* __restrict__ ws) {
    __shared__ unsigned long long lt[128];   // "<EPS" bits for positions [0,8192)
    __shared__ unsigned long long mk[64];
    const int f = blockIdx.x;
    const size_t base = (size_t)f * LEN;
    const int tid = threadIdx.x, lane = tid & 63, wv = tid >> 6;

    for (int r = 0; r < 8; ++r) {
        int p = (r << 10) + tid;
        unsigned long long bal = __ballot(in[base + p] < EPSF);
        if (lane == 0) lt[p >> 6] = bal;
    }
    __syncthreads();

    const int DLs[4] = {8, 64, 512, 4096};
    const int STs[4] = {0, 8, 72, 584};
    for (int lev = 0; lev < 4; ++lev) {
        const int dl = DLs[lev], st = STs[lev], en = st + dl;
        const int ng = (dl + 63) >> 6;
        for (int g = wv; g < ng; g += 16) {        // mask compute
            int j = (g << 6) + lane;
            bool m = false;
            if (j < dl) {
                int a = j;
                for (;;) {
                    int p = dl + a;
                    m = m || ((lt[p >> 6] >> (p & 63)) & 1ULL);
                    if (a >= st) {
                        int pa = (a - st) >> 3;
                        if (pa < a) { a = pa; continue; }
                    }
                    break;
                }
            }
            unsigned long long bal = __ballot(m);
            if (lane == 0) mk[g] = bal;
        }
        __syncthreads();
        if (lev == 3) {
            if (tid < 64) ws[(size_t)f * 64 + tid] = mk[tid];
            return;
        }
        const int hi = ((en + 8 * dl) + 63) >> 6;  // apply zeroing to lt
        for (int g = (dl >> 6) + wv; g < hi; g += 16) {
            int p = (g << 6) + lane;
            bool b = (lt[g] >> lane) & 1ULL;
            if (p >= dl && p < 2 * dl) {
                int q = p - dl;
                b = b || ((mk[q >> 6] >> (q & 63)) & 1ULL);
            }
            if (p >= en && p < en + 8 * dl) {
                int q = (p - en) >> 3;
                b = b || ((mk[q >> 6] >> (q & 63)) & 1ULL);
            }
            unsigned long long bal = __ballot(b);
            if (lane == 0) lt[g] = bal;
        }
        __syncthreads();
    }
}

// K2: one thread per (f, j) level-4 node. Masks computed inline:
//   m4[j] = lt(in[32768+j]) || [j>=4680: lt(in[32768+q]), q=(j-4680)>>3] || m3-bit.
// j <  3511: per-child masks = lt(childval) || m4[j]; write mean only.
// j >= 3511: shared m4[j]; write mean and pruned children (positions >= 65536).
// mean3 tail fused: 8-lane shuffle reduce over mean4[0..4680) -> out[7607+t].
// zero-fill fused: thread j zeroes out[base+j] for j<7607 and j in [8192,32768).
__global__ __launch_bounds__(256) void k_bulk(const float* __restrict__ in,
                                              float* __restrict__ out,
                                              const unsigned char* __restrict__ ws) {
    int t = blockIdx.x * 256 + threadIdx.x;      // 64*32768 total
    int f = t >> 15, j = t & 32767;
    size_t base = (size_t)f * LEN;
    const unsigned char* m3 = ws + (size_t)f * 512;
    const float4* s = (const float4*)(in + base + V0 + 8 * (size_t)j);
    float4 a = s[0], b = s[1];
    float own = in[base + 32768 + j];
    float mean;
    if (j < 3511) {
        int i3 = (28088 + j) >> 3;
        bool mj = (own < EPSF) || ((m3[i3 >> 3] >> (i3 & 7)) & 1);
        if (mj) {
            mean = 0.f;
        } else {
            mean = ((a.x < EPSF ? 0.f : a.x) + (a.y < EPSF ? 0.f : a.y) +
                    (a.z < EPSF ? 0.f : a.z) + (a.w < EPSF ? 0.f : a.w) +
                    (b.x < EPSF ? 0.f : b.x) + (b.y < EPSF ? 0.f : b.y) +
                    (b.z < EPSF ? 0.f : b.z) + (b.w < EPSF ? 0.f : b.w)) * 0.125f;
        }
        out[base + 32768 + j] = mean;
    } else {
        bool m;
        if (j < 4680) {
            int i3 = (28088 + j) >> 3;
            m = (own < EPSF) || ((m3[i3 >> 3] >> (i3 & 7)) & 1);
        } else {
            int q = (j - 4680) >> 3;
            int i3 = (28088 + q) >> 3;
            m = (own < EPSF) || (in[base + 32768 + q] < EPSF) ||
                ((m3[i3 >> 3] >> (i3 & 7)) & 1);
        }
        if (m) {
            a = make_float4(0.f, 0.f, 0.f, 0.f);
            b = a;
            mean = 0.f;
        } else {
            mean = (a.x + a.y + a.z + a.w + b.x + b.y + b.z + b.w) * 0.125f;
        }
        out[base + 32768 + j] = mean;
        float4* d = (float4*)(out + base + V0 + 8 * (size_t)j);
        d[0] = a;
        d[1] = b;
    }
    // fused mean3 tail (j in [0,4680), groups of 8 within one wave)
    float v = mean;
    v += __shfl_xor(v, 1);
    v += __shfl_xor(v, 2);
    v += __shfl_xor(v, 4);
    if (j < 4680 && (j & 7) == 0)
        out[base + MEAN3_OFF + (j >> 3)] = v * 0.125f;
    // fused zero-fill: regions [0,7607) and [8192,32768)
    if (j < 7607 || j >= 8192)
        out[base + j] = 0.f;
}

extern "C" void kernel_launch(void* const* d_in, const int* in_sizes, int n_in,
                              void* d_out, int out_size, void* d_ws, size_t ws_size,
                              hipStream_t stream) {
    const float* in = (const float*)d_in[0];
    float* out = (float*)d_out;

    k_m3<<<NF, 1024, 0, stream>>>(in, (unsigned long long*)d_ws);
    k_bulk<<<(NF * 32768) / 256, 256, 0, stream>>>(in, out,
                                                   (const unsigned char*)d_ws);
}

// Round 6
// 26.693 us; speedup vs baseline: 2.8062x; 1.3402x over previous
//
#include <hip/hip_runtime.h>

#define NF 64
#define LEN 299592
#define V0 37448            // voxel region start in octree
#define MEAN3_OFF 7607      // 4096 + 3511
#define EPSF 1e-5f

// Single fused kernel. One thread per (f, j) level-4 node, j in [0,32768).
// The level-0..3 prune cascade collapses to a closed form over raw inputs for
// the only consumed m3 bits (i3 in [3511,4096)):
//   m1_61 = lt(125)|lt(70)|lt(15)|lt(8)
//   m2[qq] = lt(512+qq) | lt(qq<488 ? 563 : 564) | m1_61      (qq in [484,494))
//   B[pb]  = lt(4096+pb) | m2[(3512+pb)>>3]                   (pb in [365,439))
//   m3[i3] = lt(4096+i3) | B[(i3-584)>>3]
// Level-4: m4[j] = lt(in[32768+j]) | (j>=4680: lt(in[32768+q]), q=(j-4680)>>3)
//                | m3[i3], i3=(28088+q4)>>3, q4 = j<4680 ? j : q.
// j <  3511: per-child masks lt(child)|m4[j]; write mean4 only.
// j >= 3511: shared m4[j]; write mean4 and pruned children (positions >= 65536).
// Fused: mean3 tail via 8-lane shfl reduce; zero-fill of [0,7607) и [8192,32768).
__global__ __launch_bounds__(256) void k_fused(const float* __restrict__ in,
                                               float* __restrict__ out) {
    // XCD swizzle: 8192 blocks, keep each feature's 128 blocks on one XCD
    int b = blockIdx.x;
    int chunk = (b & 7) * 1024 + (b >> 3);
    int t = chunk * 256 + threadIdx.x;
    int f = t >> 15, j = t & 32767;
    size_t base = (size_t)f * LEN;
    const float* src = in + base;

    // closed-form m3 bit (head-region reads: L2-resident, mostly wave-broadcast)
    int q4 = (j < 4680) ? j : ((j - 4680) >> 3);
    int i3 = (28088 + q4) >> 3;            // [3511, 4096)
    int pb = (i3 - 584) >> 3;              // [365, 439)
    int qq = (3512 + pb) >> 3;             // [484, 494)
    bool m1_61 = (src[125] < EPSF) || (src[70] < EPSF) ||
                 (src[15] < EPSF) || (src[8] < EPSF);
    bool m2s = (src[(qq < 488) ? 563 : 564] < EPSF) || m1_61;
    bool M2 = (src[512 + qq] < EPSF) || m2s;
    bool Bv = (src[4096 + pb] < EPSF) || M2;
    bool m3b = (src[4096 + i3] < EPSF) || Bv;

    const float4* s = (const float4*)(src + V0 + 8 * (size_t)j);
    float4 a = s[0], c = s[1];
    float own = src[32768 + j];
    float mean;
    if (j < 3511) {
        bool mj = (own < EPSF) || m3b;
        if (mj) {
            mean = 0.f;
        } else {
            mean = ((a.x < EPSF ? 0.f : a.x) + (a.y < EPSF ? 0.f : a.y) +
                    (a.z < EPSF ? 0.f : a.z) + (a.w < EPSF ? 0.f : a.w) +
                    (c.x < EPSF ? 0.f : c.x) + (c.y < EPSF ? 0.f : c.y) +
                    (c.z < EPSF ? 0.f : c.z) + (c.w < EPSF ? 0.f : c.w)) * 0.125f;
        }
        out[base + 32768 + j] = mean;
    } else {
        bool m;
        if (j < 4680) {
            m = (own < EPSF) || m3b;
        } else {
            m = (own < EPSF) || (src[32768 + q4] < EPSF) || m3b;
        }
        if (m) {
            a = make_float4(0.f, 0.f, 0.f, 0.f);
            c = a;
            mean = 0.f;
        } else {
            mean = (a.x + a.y + a.z + a.w + c.x + c.y + c.z + c.w) * 0.125f;
        }
        out[base + 32768 + j] = mean;
        float4* d = (float4*)(out + base + V0 + 8 * (size_t)j);
        d[0] = a;
        d[1] = c;
    }
    // fused mean3 tail (j in [0,4680), groups of 8 within one wave)
    float v = mean;
    v += __shfl_xor(v, 1);
    v += __shfl_xor(v, 2);
    v += __shfl_xor(v, 4);
    if (j < 4680 && (j & 7) == 0)
        out[base + MEAN3_OFF + (j >> 3)] = v * 0.125f;
    // fused zero-fill: regions [0,7607) and [8192,32768)
    if (j < 7607 || j >= 8192)
        out[base + j] = 0.f;
}

extern "C" void kernel_launch(void* const* d_in, const int* in_sizes, int n_in,
                              void* d_out, int out_size, void* d_ws, size_t ws_size,
                              hipStream_t stream) {
    const float* in = (const float*)d_in[0];
    float* out = (float*)d_out;
    k_fused<<<(NF * 32768) / 256, 256, 0, stream>>>(in, out);
}